// Round 3
// baseline (417.717 us; speedup 1.0000x reference)
//
#include <hip/hip_runtime.h>

// SNN LIF scan: T=1024, B=32, N=2048. EXACT sequential-in-T (spikes are
// binary -> trajectory must be bit-exact -> no T-parallelization, R2).
// R5: one thread per TWO adjacent neurons, float2 (v2f) loads/stores.
// R6/R7 post-mortem: deepening per-wave load prefetch (U=32) gained ~0.
// Root cause: CDNA has NO separate store counter (no vscnt). Loads and
// stores share vmcnt with STRICT in-order retirement, so every prefetch
// load issued after a store waits on that store's HBM/L2 ack; interleaved
// stores also overflow the 63-op vmcnt window. Depth cannot materialize.
// R8 (this round): decoupled access/execute.
//   - waves 0-1 (tid 0..127): COMPUTE. Pure-load vmcnt stream (xa/xb deep
//     prefetch, U=32 => 32-64 loads in flight). Spikes go to LDS
//     (lgkmcnt -- separate counter, invisible to the load pipeline).
//   - waves 2-3 (tid 128..255): WRITER. ds_read slab -> nontemporal global
//     stores. Never waits on store completion.
//   - double-buffered 64 KB LDS slab; RAW s_barrier + lgkmcnt(0) ONLY.
//     __syncthreads() would emit vmcnt(0) and drain the compute prefetch
//     every phase (the classic CDNA barrier-drain stall). Slab reuse only
//     needs lgkm: compute ds_writes drained pre-barrier; writer ds_reads
//     complete before its dependent stores issue.
// Roofline: 537 MB one-touch at measured 6.4 TB/s fill ceiling = ~85 us.
// d_out layout: spikes[T*B*N] ++ v_final[B*N] ++ i_final[B*N].

#define TT 1024
#define BN 65536           // B*N
#define BN2 (BN / 2)       // stride per timestep in vec2 units
#define U  32              // timesteps per phase
#define NPH (TT / U)       // 32 phases (even -- required by 2-phase loop)

typedef float v2f __attribute__((ext_vector_type(2)));

__global__ __launch_bounds__(256, 1) void snn_lif_kernel(
    const float* __restrict__ xf,
    float* __restrict__ outf)
{
    // slab[buf][timestep-in-phase][compute-lane] : 2*32*128*8 = 64 KB
    __shared__ v2f slab[2][U][128];

    const int tid = threadIdx.x;
    const int lane_idx = blockIdx.x * 128 + (tid & 127);   // 0..BN2-1

    if (tid < 128) {
        // ---------------- compute waves ----------------
        const v2f* __restrict__ xp = (const v2f*)xf + lane_idx;

        float v0 = 0.0f, v1 = 0.0f;
        float i0 = 0.0f, i1 = 0.0f;
        const float c_mem = 0.1f;   // fp32(DT*TAU_MEM_INV)
        const float c_syn = 0.8f;   // fp32(1 - DT*TAU_SYN_INV)

        // Exact ref op sequence; _rn intrinsics forbid FMA contraction
        // (spike decisions are binary -- must match fp32 reference
        // bit-exactly; load-bearing, do not touch).
        auto step = [&](float& v, float& i, float xin) -> float {
            float dv    = __fmul_rn(c_mem, __fadd_rn(__fsub_rn(0.0f, v), i));
            float v_dec = __fadd_rn(v, dv);
            float i_dec = __fmul_rn(i, c_syn);
            bool fired  = (v_dec > 1.0f);
            v = fired ? 0.0f : v_dec;
            i = __fadd_rn(i_dec, xin);
            return fired ? 1.0f : 0.0f;
        };

        v2f xa[U], xb[U];
        #pragma unroll
        for (int k = 0; k < U; ++k)
            xa[k] = __builtin_nontemporal_load(&xp[(size_t)k * BN2]);
        #pragma unroll
        for (int k = 0; k < U; ++k)
            xb[k] = __builtin_nontemporal_load(&xp[(size_t)(U + k) * BN2]);

        #pragma unroll 1
        for (int p = 0; p < NPH; p += 2) {
            // phase p (even): consume xa -> slab[0]
            #pragma unroll
            for (int k = 0; k < U; ++k) {
                v2f z;
                z.x = step(v0, i0, xa[k].x);
                z.y = step(v1, i1, xa[k].y);
                slab[0][k][tid] = z;
            }
            if (p + 2 < NPH) {
                #pragma unroll
                for (int k = 0; k < U; ++k)
                    xa[k] = __builtin_nontemporal_load(
                        &xp[(size_t)((p + 2) * U + k) * BN2]);
            }
            asm volatile("s_waitcnt lgkmcnt(0)" ::: "memory");
            __builtin_amdgcn_s_barrier();

            // phase p+1 (odd): consume xb -> slab[1]
            #pragma unroll
            for (int k = 0; k < U; ++k) {
                v2f z;
                z.x = step(v0, i0, xb[k].x);
                z.y = step(v1, i1, xb[k].y);
                slab[1][k][tid] = z;
            }
            if (p + 3 < NPH) {
                #pragma unroll
                for (int k = 0; k < U; ++k)
                    xb[k] = __builtin_nontemporal_load(
                        &xp[(size_t)((p + 3) * U + k) * BN2]);
            }
            asm volatile("s_waitcnt lgkmcnt(0)" ::: "memory");
            __builtin_amdgcn_s_barrier();
        }

        // Final state (vec2 contiguous in both v and i regions).
        v2f* vf  = (v2f*)(outf + (size_t)TT * BN) + lane_idx;
        v2f* iff = (v2f*)(outf + (size_t)TT * BN + BN) + lane_idx;
        v2f a; a.x = v0; a.y = v1; *vf = a;
        v2f b; b.x = i0; b.y = i1; *iff = b;
    } else {
        // ---------------- writer waves ----------------
        v2f* __restrict__ sp = (v2f*)outf + lane_idx;
        const int wtid = tid - 128;

        #pragma unroll 1
        for (int p = 0; p < NPH; p += 2) {
            // drain previous odd phase (p-1) from slab[1]
            if (p > 0) {
                #pragma unroll
                for (int k = 0; k < U; ++k) {
                    v2f z = slab[1][k][wtid];
                    __builtin_nontemporal_store(
                        z, &sp[(size_t)((p - 1) * U + k) * BN2]);
                }
            }
            asm volatile("s_waitcnt lgkmcnt(0)" ::: "memory");
            __builtin_amdgcn_s_barrier();

            // drain even phase p from slab[0]
            #pragma unroll
            for (int k = 0; k < U; ++k) {
                v2f z = slab[0][k][wtid];
                __builtin_nontemporal_store(
                    z, &sp[(size_t)(p * U + k) * BN2]);
            }
            asm volatile("s_waitcnt lgkmcnt(0)" ::: "memory");
            __builtin_amdgcn_s_barrier();
        }
        // drain final odd phase NPH-1 from slab[1]
        #pragma unroll
        for (int k = 0; k < U; ++k) {
            v2f z = slab[1][k][wtid];
            __builtin_nontemporal_store(
                z, &sp[(size_t)((NPH - 1) * U + k) * BN2]);
        }
    }
}

extern "C" void kernel_launch(void* const* d_in, const int* in_sizes, int n_in,
                              void* d_out, int out_size, void* d_ws, size_t ws_size,
                              hipStream_t stream) {
    const float* x = (const float*)d_in[0];
    float* out = (float*)d_out;
    // 256 blocks x 256 threads: 1 block/CU; waves 0-1 compute, 2-3 write.
    snn_lif_kernel<<<BN2 / 128, 256, 0, stream>>>(x, out);
}